// Round 1
// baseline (2482.366 us; speedup 1.0000x reference)
//
#include <hip/hip_runtime.h>
#include <hip/hip_bf16.h>
#include <math.h>

// GPT forward, bf16 MFMA GEMMs + f32 residual stream.
// Dims: L=4, B=2, S=1024, E=1024, H=16, HD=64, FF=6144, V=32000, tokens T=2048.

typedef unsigned short ushort_t;
typedef unsigned short us8 __attribute__((ext_vector_type(8)));
typedef unsigned short us4 __attribute__((ext_vector_type(4)));
typedef __bf16 bf16x8 __attribute__((ext_vector_type(8)));
typedef float f32x4 __attribute__((ext_vector_type(4)));

#define LN_EPS 1e-5f

__device__ inline ushort_t f2bf(float f) {
    union { float f; unsigned u; } v; v.f = f;
    unsigned r = v.u + 0x7FFFu + ((v.u >> 16) & 1u);   // RNE
    return (ushort_t)(r >> 16);
}

// ---------------------------------------------------------------------------
// Generic GEMM: C[M,N] = A[M,K] * Bt[N,K]^T, A/Bt bf16 row-major (K contig).
// 64x64 tile, BK=64, 4 waves (2x2), each wave 32x32 via 2x2 MFMA 16x16x32.
// EPI: 0 = f32 store (*alpha), 1 = bf16 store, 2 = f32 add-in-place,
//      3 = GELU(exact) -> bf16, 4 = bf16 TRANSPOSED store (C[col*ldc+row]).
// ---------------------------------------------------------------------------
enum { EPI_F32 = 0, EPI_BF16 = 1, EPI_ADDF32 = 2, EPI_GELU = 3, EPI_TBF16 = 4 };

template<int EPI, bool CSKIP, bool KLIM>
__global__ __launch_bounds__(256)
void gemm_bt(const ushort_t* __restrict__ A, const ushort_t* __restrict__ B,
             void* __restrict__ Cv,
             int M, int N, int K, int lda, int ldb, int ldc,
             long bsA, long bsB, long bsC, float alpha)
{
    const int m0 = blockIdx.y * 64;
    const int n0 = blockIdx.x * 64;
    if (CSKIP && n0 > m0 + 63) return;   // causal: block entirely above diagonal

    A += (long)blockIdx.z * bsA;
    B += (long)blockIdx.z * bsB;

    __shared__ __align__(16) ushort_t As[64][72];  // stride 144B (16B-aligned)
    __shared__ __align__(16) ushort_t Bs[64][72];

    const int tid  = threadIdx.x;
    const int lane = tid & 63;
    const int wid  = tid >> 6;
    const int wr   = wid >> 1, wc = wid & 1;

    f32x4 acc[2][2] = {};

    const int kend = KLIM ? ((m0 + 64 < K) ? (m0 + 64) : K) : K;

    for (int k0 = 0; k0 < kend; k0 += 64) {
        #pragma unroll
        for (int i = 0; i < 2; ++i) {
            int c  = tid + i * 256;
            int r  = c >> 3;
            int ko = (c & 7) * 8;
            *(us8*)&As[r][ko] = *(const us8*)&A[(long)(m0 + r) * lda + k0 + ko];
            *(us8*)&Bs[r][ko] = *(const us8*)&B[(long)(n0 + r) * ldb + k0 + ko];
        }
        __syncthreads();
        #pragma unroll
        for (int kk = 0; kk < 2; ++kk) {
            const int krd = kk * 32 + (lane >> 4) * 8;
            bf16x8 a[2], b[2];
            #pragma unroll
            for (int mi = 0; mi < 2; ++mi)
                a[mi] = __builtin_bit_cast(bf16x8,
                        *(const us8*)&As[wr * 32 + mi * 16 + (lane & 15)][krd]);
            #pragma unroll
            for (int ni = 0; ni < 2; ++ni)
                b[ni] = __builtin_bit_cast(bf16x8,
                        *(const us8*)&Bs[wc * 32 + ni * 16 + (lane & 15)][krd]);
            #pragma unroll
            for (int mi = 0; mi < 2; ++mi)
                #pragma unroll
                for (int ni = 0; ni < 2; ++ni)
                    acc[mi][ni] = __builtin_amdgcn_mfma_f32_16x16x32_bf16(
                        a[mi], b[ni], acc[mi][ni], 0, 0, 0);
        }
        __syncthreads();
    }

    const int rbase = m0 + wr * 32 + (lane >> 4) * 4;
    const int cbase = n0 + wc * 32 + (lane & 15);

    #pragma unroll
    for (int mi = 0; mi < 2; ++mi) {
        #pragma unroll
        for (int ni = 0; ni < 2; ++ni) {
            const int colg = cbase + ni * 16;
            if (EPI == EPI_TBF16) {
                ushort_t* C = (ushort_t*)Cv + (long)blockIdx.z * bsC;
                us4 o4;
                #pragma unroll
                for (int r = 0; r < 4; ++r) o4[r] = f2bf(acc[mi][ni][r]);
                *(us4*)&C[(long)colg * ldc + rbase + mi * 16] = o4;
            } else {
                #pragma unroll
                for (int r = 0; r < 4; ++r) {
                    const int  rowg = rbase + mi * 16 + r;
                    const long off  = (long)rowg * ldc + colg;
                    const float val = acc[mi][ni][r];
                    if (EPI == EPI_F32) {
                        float* C = (float*)Cv + (long)blockIdx.z * bsC;
                        C[off] = val * alpha;
                    } else if (EPI == EPI_BF16) {
                        ushort_t* C = (ushort_t*)Cv + (long)blockIdx.z * bsC;
                        C[off] = f2bf(val);
                    } else if (EPI == EPI_ADDF32) {
                        float* C = (float*)Cv + (long)blockIdx.z * bsC;
                        C[off] += val;
                    } else { // EPI_GELU
                        ushort_t* C = (ushort_t*)Cv + (long)blockIdx.z * bsC;
                        float g = 0.5f * val * (1.0f + erff(val * 0.70710678118654752f));
                        C[off] = f2bf(g);
                    }
                }
            }
        }
    }
}

// ---------------------------------------------------------------------------
// Tiled transpose + f32->bf16 convert: out[n*ldout+k] = bf16(in[k*ldin+n])
// block (32,8), 32x32 tiles. All dims used are multiples of 32.
// ---------------------------------------------------------------------------
__global__ __launch_bounds__(256)
void transpose_conv(const float* __restrict__ in, ushort_t* __restrict__ out,
                    long ldin, long ldout, long bsin, long bsout)
{
    __shared__ float tile[32][33];
    const int tx = threadIdx.x, ty = threadIdx.y;
    const long bin  = (long)blockIdx.z * bsin;
    const long bout = (long)blockIdx.z * bsout;
    const int n0 = blockIdx.x * 32, k0 = blockIdx.y * 32;
    #pragma unroll
    for (int i = 0; i < 4; ++i)
        tile[ty + i * 8][tx] = in[bin + (long)(k0 + ty + i * 8) * ldin + n0 + tx];
    __syncthreads();
    #pragma unroll
    for (int i = 0; i < 4; ++i) {
        const int n = ty + i * 8;
        out[bout + (long)(n0 + n) * ldout + k0 + tx] = f2bf(tile[tx][n]);
    }
}

// ---------------------------------------------------------------------------
// h[row,:] = emb[x[row],:] + pos[row%1024,:]     (grid = 2048 rows, 256 thr)
// ---------------------------------------------------------------------------
__global__ __launch_bounds__(256)
void embed_kernel(const int* __restrict__ x, const float* __restrict__ emb,
                  const float* __restrict__ pos, float* __restrict__ h)
{
    const int row = blockIdx.x, tid = threadIdx.x;
    const int s = row & 1023;
    const int idx = x[row];
    const float4 e = ((const float4*)(emb + (long)idx * 1024))[tid];
    const float4 p = ((const float4*)(pos + (long)s * 1024))[tid];
    float4 o; o.x = e.x + p.x; o.y = e.y + p.y; o.z = e.z + p.z; o.w = e.w + p.w;
    ((float4*)(h + (long)row * 1024))[tid] = o;
}

// ---------------------------------------------------------------------------
// LayerNorm over E=1024: z = bf16((x-mu)*rstd*g + b).  One block per row.
// ---------------------------------------------------------------------------
__global__ __launch_bounds__(256)
void ln_kernel(const float* __restrict__ x, const float* __restrict__ g,
               const float* __restrict__ b, ushort_t* __restrict__ z)
{
    const int row = blockIdx.x, tid = threadIdx.x;
    const float4 v = ((const float4*)(x + (long)row * 1024))[tid];
    float s  = v.x + v.y + v.z + v.w;
    float sq = v.x * v.x + v.y * v.y + v.z * v.z + v.w * v.w;
    #pragma unroll
    for (int o = 32; o > 0; o >>= 1) { s += __shfl_down(s, o); sq += __shfl_down(sq, o); }
    __shared__ float ls[4], lq[4];
    if ((tid & 63) == 0) { ls[tid >> 6] = s; lq[tid >> 6] = sq; }
    __syncthreads();
    s  = ls[0] + ls[1] + ls[2] + ls[3];
    sq = lq[0] + lq[1] + lq[2] + lq[3];
    const float mu   = s * (1.0f / 1024.0f);
    const float var  = sq * (1.0f / 1024.0f) - mu * mu;
    const float rstd = rsqrtf(var + LN_EPS);
    const float4 gg = ((const float4*)g)[tid];
    const float4 bb = ((const float4*)b)[tid];
    us4 o4;
    o4[0] = f2bf((v.x - mu) * rstd * gg.x + bb.x);
    o4[1] = f2bf((v.y - mu) * rstd * gg.y + bb.y);
    o4[2] = f2bf((v.z - mu) * rstd * gg.z + bb.z);
    o4[3] = f2bf((v.w - mu) * rstd * gg.w + bb.w);
    *(us4*)(z + (long)row * 1024 + tid * 4) = o4;
}

// ---------------------------------------------------------------------------
// Causal softmax over one score row (prefix [0..s]); writes bf16 P (0 beyond s).
// grid = 16 heads * 1024 rows (per batch chunk).
// ---------------------------------------------------------------------------
__global__ __launch_bounds__(256)
void softmax_kernel(const float* __restrict__ sc, ushort_t* __restrict__ P)
{
    const int rid = blockIdx.x;
    const int hh = rid >> 10, s = rid & 1023;
    const float* srow = sc + (long)hh * 1048576 + (long)s * 1024;
    ushort_t*    prow = P  + (long)hh * 1048576 + (long)s * 1024;
    const int tid = threadIdx.x;

    float m = -INFINITY;
    for (int t = tid; t <= s; t += 256) m = fmaxf(m, srow[t]);
    #pragma unroll
    for (int o = 1; o < 64; o <<= 1) m = fmaxf(m, __shfl_xor(m, o));
    __shared__ float red[4];
    if ((tid & 63) == 0) red[tid >> 6] = m;
    __syncthreads();
    m = fmaxf(fmaxf(red[0], red[1]), fmaxf(red[2], red[3]));
    __syncthreads();

    float sum = 0.0f;
    for (int t = tid; t <= s; t += 256) sum += __expf(srow[t] - m);
    #pragma unroll
    for (int o = 1; o < 64; o <<= 1) sum += __shfl_xor(sum, o);
    if ((tid & 63) == 0) red[tid >> 6] = sum;
    __syncthreads();
    sum = red[0] + red[1] + red[2] + red[3];
    const float rinv = 1.0f / sum;

    for (int t = tid; t < 1024; t += 256)
        prow[t] = (t <= s) ? f2bf(__expf(srow[t] - m) * rinv) : (ushort_t)0;
}

// ---------------------------------------------------------------------------
extern "C" void kernel_launch(void* const* d_in, const int* in_sizes, int n_in,
                              void* d_out, int out_size, void* d_ws, size_t ws_size,
                              hipStream_t stream)
{
    const int*   x   = (const int*)  d_in[0];
    const float* emb = (const float*)d_in[1];
    const float* pos = (const float*)d_in[2];
    const float* Wq  = (const float*)d_in[3];
    const float* Wk  = (const float*)d_in[4];
    const float* Wv  = (const float*)d_in[5];
    const float* Wo  = (const float*)d_in[6];
    const float* g1  = (const float*)d_in[7];
    const float* b1  = (const float*)d_in[8];
    const float* g2  = (const float*)d_in[9];
    const float* b2  = (const float*)d_in[10];
    const float* W1  = (const float*)d_in[11];
    const float* W2  = (const float*)d_in[12];
    const float* gf  = (const float*)d_in[13];
    const float* bfp = (const float*)d_in[14];
    const float* Wf  = (const float*)d_in[15];
    float* out = (float*)d_out;

    char* ws = (char*)d_ws;
    size_t off = 0;
    auto alloc = [&](size_t bytes) {
        char* p = ws + off;
        off = (off + bytes + 255) & ~(size_t)255;
        return p;
    };
    ushort_t* WqT = (ushort_t*)alloc(4UL * 1048576 * 2);
    ushort_t* WkT = (ushort_t*)alloc(4UL * 1048576 * 2);
    ushort_t* WvT = (ushort_t*)alloc(4UL * 1048576 * 2);
    ushort_t* WoT = (ushort_t*)alloc(4UL * 1048576 * 2);
    ushort_t* W1T = (ushort_t*)alloc(4UL * 6291456 * 2);
    ushort_t* W2T = (ushort_t*)alloc(4UL * 6291456 * 2);
    ushort_t* WfT = (ushort_t*)alloc(32768000UL * 2);
    float*    h   = (float*)   alloc(2048UL * 1024 * 4);
    ushort_t* z   = (ushort_t*)alloc(2048UL * 1024 * 2);
    ushort_t* qb  = (ushort_t*)alloc(2048UL * 1024 * 2);
    ushort_t* kb  = (ushort_t*)alloc(2048UL * 1024 * 2);
    ushort_t* vT  = (ushort_t*)alloc(2048UL * 1024 * 2);
    ushort_t* ob  = (ushort_t*)alloc(2048UL * 1024 * 2);
    ushort_t* ub  = (ushort_t*)alloc(2048UL * 6144 * 2);
    float*    scb = (float*)   alloc(16UL * 1048576 * 4);
    ushort_t* Pb  = (ushort_t*)alloc(16UL * 1048576 * 2);
    (void)ws_size; (void)in_sizes; (void)n_in; (void)out_size;

    const dim3 tb(32, 8);
    // Weight transposes (f32 -> bf16, B^T layout), once per call.
    transpose_conv<<<dim3(2,   32, 64), tb, 0, stream>>>(Wq, WqT, 64,    1024, 65536,   65536);
    transpose_conv<<<dim3(2,   32, 64), tb, 0, stream>>>(Wk, WkT, 64,    1024, 65536,   65536);
    transpose_conv<<<dim3(2,   32, 64), tb, 0, stream>>>(Wv, WvT, 64,    1024, 65536,   65536);
    transpose_conv<<<dim3(32,  32,  4), tb, 0, stream>>>(Wo, WoT, 1024,  1024, 1048576, 1048576);
    transpose_conv<<<dim3(192, 32,  4), tb, 0, stream>>>(W1, W1T, 6144,  1024, 6291456, 6291456);
    transpose_conv<<<dim3(32, 192,  4), tb, 0, stream>>>(W2, W2T, 1024,  6144, 6291456, 6291456);
    transpose_conv<<<dim3(1000,32,  1), tb, 0, stream>>>(Wf, WfT, 32000, 1024, 0,       0);

    embed_kernel<<<2048, 256, 0, stream>>>(x, emb, pos, h);

    for (int l = 0; l < 4; ++l) {
        const size_t wsq = (size_t)l * 1048576;   // per-layer stride, E*E
        const size_t wff = (size_t)l * 6291456;   // per-layer stride, E*FF

        ln_kernel<<<2048, 256, 0, stream>>>(h, g1 + l * 1024, b1 + l * 1024, z);

        // q, k: [2048,1024] = z @ WqT^T
        gemm_bt<EPI_BF16, false, false><<<dim3(16, 32, 1), 256, 0, stream>>>(
            z, WqT + wsq, qb, 2048, 1024, 1024, 1024, 1024, 1024, 0, 0, 0, 1.0f);
        gemm_bt<EPI_BF16, false, false><<<dim3(16, 32, 1), 256, 0, stream>>>(
            z, WkT + wsq, kb, 2048, 1024, 1024, 1024, 1024, 1024, 0, 0, 0, 1.0f);
        // v, stored transposed per batch: vT[b][h*64+d][s]
        gemm_bt<EPI_TBF16, false, false><<<dim3(16, 16, 2), 256, 0, stream>>>(
            z, WvT + wsq, vT, 1024, 1024, 1024, 1024, 1024, 1024,
            1048576, 0, 1048576, 1.0f);

        for (int b = 0; b < 2; ++b) {
            const long boff = (long)b * 1048576;
            // scores[h][s][t] = 0.125 * q . k   (batched over 16 heads, causal skip)
            gemm_bt<EPI_F32, true, false><<<dim3(16, 16, 16), 256, 0, stream>>>(
                qb + boff, kb + boff, scb, 1024, 1024, 64, 1024, 1024, 1024,
                64, 64, 1048576, 0.125f);
            softmax_kernel<<<16384, 256, 0, stream>>>(scb, Pb);
            // O[h][s][d] = P @ V  (K limited to causal prefix), write into concat o
            gemm_bt<EPI_BF16, false, true><<<dim3(1, 16, 16), 256, 0, stream>>>(
                Pb, vT + boff, ob + boff, 1024, 64, 1024, 1024, 1024, 1024,
                1048576, 65536, 64, 1.0f);
        }

        // h += o @ Wo
        gemm_bt<EPI_ADDF32, false, false><<<dim3(16, 32, 1), 256, 0, stream>>>(
            ob, WoT + wsq, h, 2048, 1024, 1024, 1024, 1024, 1024, 0, 0, 0, 1.0f);

        ln_kernel<<<2048, 256, 0, stream>>>(h, g2 + l * 1024, b2 + l * 1024, z);

        // u = gelu(z @ W1)
        gemm_bt<EPI_GELU, false, false><<<dim3(96, 32, 1), 256, 0, stream>>>(
            z, W1T + wff, ub, 2048, 6144, 1024, 1024, 1024, 6144, 0, 0, 0, 1.0f);
        // h += u @ W2
        gemm_bt<EPI_ADDF32, false, false><<<dim3(16, 32, 1), 256, 0, stream>>>(
            ub, W2T + wff, h, 2048, 1024, 6144, 6144, 6144, 1024, 0, 0, 0, 1.0f);
    }

    ln_kernel<<<2048, 256, 0, stream>>>(h, gf, bfp, z);
    // logits = z @ Wf  -> f32 out [2048, 32000]
    gemm_bt<EPI_F32, false, false><<<dim3(500, 32, 1), 256, 0, stream>>>(
        z, WfT, out, 2048, 32000, 1024, 1024, 1024, 32000, 0, 0, 0, 1.0f);
}

// Round 2
// 1808.176 us; speedup vs baseline: 1.3729x; 1.3729x over previous
//
#include <hip/hip_runtime.h>
#include <hip/hip_bf16.h>
#include <math.h>

// GPT forward, bf16 MFMA GEMMs + f32 residual stream.
// Dims: L=4, B=2, S=1024, E=1024, H=16, HD=64, FF=6144, V=32000, tokens T=2048.

typedef unsigned short ushort_t;
typedef unsigned short us8 __attribute__((ext_vector_type(8)));
typedef unsigned short us4 __attribute__((ext_vector_type(4)));
typedef __bf16 bf16x8 __attribute__((ext_vector_type(8)));
typedef float f32x4 __attribute__((ext_vector_type(4)));

#define LN_EPS 1e-5f

__device__ inline ushort_t f2bf(float f) {
    union { float f; unsigned u; } v; v.f = f;
    unsigned r = v.u + 0x7FFFu + ((v.u >> 16) & 1u);   // RNE
    return (ushort_t)(r >> 16);
}

#define GLD_LDS16(gp, lp)                                                  \
    __builtin_amdgcn_global_load_lds(                                      \
        (const __attribute__((address_space(1))) unsigned int*)(gp),       \
        (__attribute__((address_space(3))) unsigned int*)(lp), 16, 0, 0)

// ---------------------------------------------------------------------------
// GEMM: C[M,N] = A[M,K] * Bt[N,K]^T, A/Bt bf16 row-major (K contiguous).
// Tile BM x 128 (BM = MT*32), BK=64. 4 waves (2x2); wave = (MT*16) x 64 out
// via MT x 4 MFMA 16x16x32 frags. Staging via global_load_lds width-16
// (linear LDS, m97 structure). blockIdx.x = m-tile (fast), .y = n-tile.
// ---------------------------------------------------------------------------
enum { EPI_F32 = 0, EPI_BF16 = 1, EPI_ADDF32 = 2, EPI_GELU = 3, EPI_TBF16 = 4 };

template<int EPI, int MT>
__global__ __launch_bounds__(256)
void gemm128(const ushort_t* __restrict__ A, const ushort_t* __restrict__ B,
             void* __restrict__ Cv, int K, int lda, int ldb, int ldc,
             long bsA, long bsB, long bsC, float alpha)
{
    const int m0 = blockIdx.x * (MT * 32);
    const int n0 = blockIdx.y * 128;
    A += (long)blockIdx.z * bsA;
    B += (long)blockIdx.z * bsB;

    __shared__ __align__(16) ushort_t As[MT * 32][64];
    __shared__ __align__(16) ushort_t Bs[128][64];

    const int tid  = threadIdx.x;
    const int lane = tid & 63;
    const int wid  = tid >> 6;
    const int wr   = wid >> 1, wc = wid & 1;
    const int lr   = lane >> 3;        // staging row within 8-row stripe
    const int lc   = (lane & 7) * 8;   // staging col (elements)
    const int cg   = lane >> 4;        // 0..3
    const int cl   = lane & 15;

    f32x4 acc[MT][4] = {};

    for (int k0 = 0; k0 < K; k0 += 64) {
        #pragma unroll
        for (int j = 0; j < MT; ++j) {
            const int r = wid * (8 * MT) + j * 8;
            GLD_LDS16(&A[(long)(m0 + r + lr) * lda + k0 + lc], &As[r][0]);
        }
        #pragma unroll
        for (int j = 0; j < 4; ++j) {
            const int r = wid * 32 + j * 8;
            GLD_LDS16(&B[(long)(n0 + r + lr) * ldb + k0 + lc], &Bs[r][0]);
        }
        __syncthreads();
        #pragma unroll
        for (int kk = 0; kk < 2; ++kk) {
            const int krd = kk * 32 + cg * 8;
            bf16x8 af[MT], bfr[4];
            #pragma unroll
            for (int mi = 0; mi < MT; ++mi)
                af[mi] = __builtin_bit_cast(bf16x8,
                    *(const us8*)&As[wr * (MT * 16) + mi * 16 + cl][krd]);
            #pragma unroll
            for (int nj = 0; nj < 4; ++nj)
                bfr[nj] = __builtin_bit_cast(bf16x8,
                    *(const us8*)&Bs[wc * 64 + nj * 16 + cl][krd]);
            #pragma unroll
            for (int mi = 0; mi < MT; ++mi)
                #pragma unroll
                for (int nj = 0; nj < 4; ++nj)
                    acc[mi][nj] = __builtin_amdgcn_mfma_f32_16x16x32_bf16(
                        af[mi], bfr[nj], acc[mi][nj], 0, 0, 0);
        }
        __syncthreads();
    }

    const int rb = m0 + wr * (MT * 16) + cg * 4;
    const int cb = n0 + wc * 64 + cl;

    #pragma unroll
    for (int mi = 0; mi < MT; ++mi) {
        #pragma unroll
        for (int nj = 0; nj < 4; ++nj) {
            const int colg = cb + nj * 16;
            if (EPI == EPI_TBF16) {
                ushort_t* C = (ushort_t*)Cv + (long)blockIdx.z * bsC;
                us4 o4;
                #pragma unroll
                for (int r = 0; r < 4; ++r) o4[r] = f2bf(acc[mi][nj][r]);
                *(us4*)&C[(long)colg * ldc + rb + mi * 16] = o4;
            } else {
                #pragma unroll
                for (int r = 0; r < 4; ++r) {
                    const int  rowg = rb + mi * 16 + r;
                    const long off  = (long)rowg * ldc + colg;
                    const float val = acc[mi][nj][r];
                    if (EPI == EPI_F32) {
                        float* C = (float*)Cv + (long)blockIdx.z * bsC;
                        C[off] = val * alpha;
                    } else if (EPI == EPI_BF16) {
                        ushort_t* C = (ushort_t*)Cv + (long)blockIdx.z * bsC;
                        C[off] = f2bf(val);
                    } else if (EPI == EPI_ADDF32) {
                        float* C = (float*)Cv + (long)blockIdx.z * bsC;
                        C[off] += val;
                    } else { // EPI_GELU
                        ushort_t* C = (ushort_t*)Cv + (long)blockIdx.z * bsC;
                        float g = 0.5f * val * (1.0f + erff(val * 0.70710678118654752f));
                        C[off] = f2bf(g);
                    }
                }
            }
        }
    }
}

// ---------------------------------------------------------------------------
// Fused causal flash attention. Grid (16 qtiles, 16 heads, 2 batch), 256 thr.
// Block = 64 Q rows; wave w owns 16 rows. Per key-tile (64 keys):
//   S = Q K^T (MFMA), online softmax in registers (row stats via shfl_xor
//   over low-4 lane bits), P -> per-wave padded LDS -> A-frags, O += P V.
// V consumed directly from vT[b][h*64+d][s] (key-contiguous) as B-frags.
// ---------------------------------------------------------------------------
__global__ __launch_bounds__(256)
void flash_attn(const ushort_t* __restrict__ qb, const ushort_t* __restrict__ kb,
                const ushort_t* __restrict__ vT, ushort_t* __restrict__ ob)
{
    const int qt = gridDim.x - 1 - blockIdx.x;   // heavy blocks dispatch first
    const int hh = blockIdx.y;
    const int bb = blockIdx.z;
    const int lane = threadIdx.x & 63;
    const int w    = threadIdx.x >> 6;
    const int cg   = lane >> 4;    // 0..3
    const int cl   = lane & 15;

    __shared__ __align__(16) ushort_t P_lds[4][16][72];  // +8 pad: 2-way banks

    const int q0 = qt * 64;
    const long tokQ = (long)bb * 1024 + q0 + w * 16 + cl;

    bf16x8 qf[2];
    #pragma unroll
    for (int kk = 0; kk < 2; ++kk)
        qf[kk] = __builtin_bit_cast(bf16x8,
            *(const us8*)&qb[tokQ * 1024 + hh * 64 + kk * 32 + cg * 8]);

    const ushort_t* kbase = kb + (long)bb * 1048576 + hh * 64;
    const ushort_t* vbase = vT + (long)bb * 1048576 + (long)hh * 65536;

    f32x4 o[4] = {};
    float m4[4], l4[4];
    #pragma unroll
    for (int r = 0; r < 4; ++r) { m4[r] = -1e30f; l4[r] = 0.0f; }

    for (int tt = 0; tt <= qt; ++tt) {
        const int t0 = tt * 64;
        f32x4 s[4] = {};
        #pragma unroll
        for (int nj = 0; nj < 4; ++nj) {
            const ushort_t* kp = kbase + (long)(t0 + nj * 16 + cl) * 1024 + cg * 8;
            bf16x8 kf0 = __builtin_bit_cast(bf16x8, *(const us8*)kp);
            bf16x8 kf1 = __builtin_bit_cast(bf16x8, *(const us8*)(kp + 32));
            s[nj] = __builtin_amdgcn_mfma_f32_16x16x32_bf16(qf[0], kf0, s[nj], 0, 0, 0);
            s[nj] = __builtin_amdgcn_mfma_f32_16x16x32_bf16(qf[1], kf1, s[nj], 0, 0, 0);
        }
        // scale + causal mask + row max
        const bool diag = (tt == qt);
        float pm[4] = {-3e30f, -3e30f, -3e30f, -3e30f};
        #pragma unroll
        for (int nj = 0; nj < 4; ++nj)
            #pragma unroll
            for (int r = 0; r < 4; ++r) {
                float v = s[nj][r] * 0.125f;
                if (diag && (t0 + nj * 16 + cl) > (q0 + w * 16 + cg * 4 + r))
                    v = -1e30f;
                s[nj][r] = v;
                pm[r] = fmaxf(pm[r], v);
            }
        #pragma unroll
        for (int r = 0; r < 4; ++r)
            #pragma unroll
            for (int msk = 1; msk < 16; msk <<= 1)
                pm[r] = fmaxf(pm[r], __shfl_xor(pm[r], msk));
        float al[4], ps[4];
        #pragma unroll
        for (int r = 0; r < 4; ++r) {
            const float mn = fmaxf(m4[r], pm[r]);
            al[r] = __expf(m4[r] - mn);
            m4[r] = mn;
            ps[r] = 0.0f;
        }
        #pragma unroll
        for (int nj = 0; nj < 4; ++nj)
            #pragma unroll
            for (int r = 0; r < 4; ++r) {
                const float p = __expf(s[nj][r] - m4[r]);
                s[nj][r] = p;
                ps[r] += p;
            }
        #pragma unroll
        for (int r = 0; r < 4; ++r) {
            #pragma unroll
            for (int msk = 1; msk < 16; msk <<= 1)
                ps[r] += __shfl_xor(ps[r], msk);
            l4[r] = l4[r] * al[r] + ps[r];
        }
        #pragma unroll
        for (int nj = 0; nj < 4; ++nj)
            #pragma unroll
            for (int r = 0; r < 4; ++r) o[nj][r] *= al[r];
        // P -> LDS (wave-local tile)
        #pragma unroll
        for (int nj = 0; nj < 4; ++nj)
            #pragma unroll
            for (int r = 0; r < 4; ++r)
                P_lds[w][cg * 4 + r][nj * 16 + cl] = f2bf(s[nj][r]);
        __syncthreads();   // intra-wave write->read ordering (conservative)
        bf16x8 pa[2];
        #pragma unroll
        for (int kk = 0; kk < 2; ++kk)
            pa[kk] = __builtin_bit_cast(bf16x8,
                *(const us8*)&P_lds[w][cl][kk * 32 + cg * 8]);
        #pragma unroll
        for (int nj = 0; nj < 4; ++nj) {
            const ushort_t* vp = vbase + (long)(nj * 16 + cl) * 1024 + t0 + cg * 8;
            bf16x8 vf0 = __builtin_bit_cast(bf16x8, *(const us8*)vp);
            bf16x8 vf1 = __builtin_bit_cast(bf16x8, *(const us8*)(vp + 32));
            o[nj] = __builtin_amdgcn_mfma_f32_16x16x32_bf16(pa[0], vf0, o[nj], 0, 0, 0);
            o[nj] = __builtin_amdgcn_mfma_f32_16x16x32_bf16(pa[1], vf1, o[nj], 0, 0, 0);
        }
    }

    #pragma unroll
    for (int r = 0; r < 4; ++r) {
        const float inv = 1.0f / l4[r];
        const long tok = (long)bb * 1024 + q0 + w * 16 + cg * 4 + r;
        #pragma unroll
        for (int nj = 0; nj < 4; ++nj)
            ob[tok * 1024 + hh * 64 + nj * 16 + cl] = f2bf(o[nj][r] * inv);
    }
}

// ---------------------------------------------------------------------------
// Tiled transpose + f32->bf16 convert: out[n*ldout+k] = bf16(in[k*ldin+n])
// ---------------------------------------------------------------------------
__global__ __launch_bounds__(256)
void transpose_conv(const float* __restrict__ in, ushort_t* __restrict__ out,
                    long ldin, long ldout, long bsin, long bsout)
{
    __shared__ float tile[32][33];
    const int tx = threadIdx.x, ty = threadIdx.y;
    const long bin  = (long)blockIdx.z * bsin;
    const long bout = (long)blockIdx.z * bsout;
    const int n0 = blockIdx.x * 32, k0 = blockIdx.y * 32;
    #pragma unroll
    for (int i = 0; i < 4; ++i)
        tile[ty + i * 8][tx] = in[bin + (long)(k0 + ty + i * 8) * ldin + n0 + tx];
    __syncthreads();
    #pragma unroll
    for (int i = 0; i < 4; ++i) {
        const int n = ty + i * 8;
        out[bout + (long)(n0 + n) * ldout + k0 + tx] = f2bf(tile[tx][n]);
    }
}

// ---------------------------------------------------------------------------
__global__ __launch_bounds__(256)
void embed_kernel(const int* __restrict__ x, const float* __restrict__ emb,
                  const float* __restrict__ pos, float* __restrict__ h)
{
    const int row = blockIdx.x, tid = threadIdx.x;
    const int s = row & 1023;
    const int idx = x[row];
    const float4 e = ((const float4*)(emb + (long)idx * 1024))[tid];
    const float4 p = ((const float4*)(pos + (long)s * 1024))[tid];
    float4 o; o.x = e.x + p.x; o.y = e.y + p.y; o.z = e.z + p.z; o.w = e.w + p.w;
    ((float4*)(h + (long)row * 1024))[tid] = o;
}

// ---------------------------------------------------------------------------
__global__ __launch_bounds__(256)
void ln_kernel(const float* __restrict__ x, const float* __restrict__ g,
               const float* __restrict__ b, ushort_t* __restrict__ z)
{
    const int row = blockIdx.x, tid = threadIdx.x;
    const float4 v = ((const float4*)(x + (long)row * 1024))[tid];
    float s  = v.x + v.y + v.z + v.w;
    float sq = v.x * v.x + v.y * v.y + v.z * v.z + v.w * v.w;
    #pragma unroll
    for (int o = 32; o > 0; o >>= 1) { s += __shfl_down(s, o); sq += __shfl_down(sq, o); }
    __shared__ float ls[4], lq[4];
    if ((tid & 63) == 0) { ls[tid >> 6] = s; lq[tid >> 6] = sq; }
    __syncthreads();
    s  = ls[0] + ls[1] + ls[2] + ls[3];
    sq = lq[0] + lq[1] + lq[2] + lq[3];
    const float mu   = s * (1.0f / 1024.0f);
    const float var  = sq * (1.0f / 1024.0f) - mu * mu;
    const float rstd = rsqrtf(var + LN_EPS);
    const float4 gg = ((const float4*)g)[tid];
    const float4 bb = ((const float4*)b)[tid];
    us4 o4;
    o4[0] = f2bf((v.x - mu) * rstd * gg.x + bb.x);
    o4[1] = f2bf((v.y - mu) * rstd * gg.y + bb.y);
    o4[2] = f2bf((v.z - mu) * rstd * gg.z + bb.z);
    o4[3] = f2bf((v.w - mu) * rstd * gg.w + bb.w);
    *(us4*)(z + (long)row * 1024 + tid * 4) = o4;
}

// ---------------------------------------------------------------------------
extern "C" void kernel_launch(void* const* d_in, const int* in_sizes, int n_in,
                              void* d_out, int out_size, void* d_ws, size_t ws_size,
                              hipStream_t stream)
{
    const int*   x   = (const int*)  d_in[0];
    const float* emb = (const float*)d_in[1];
    const float* pos = (const float*)d_in[2];
    const float* Wq  = (const float*)d_in[3];
    const float* Wk  = (const float*)d_in[4];
    const float* Wv  = (const float*)d_in[5];
    const float* Wo  = (const float*)d_in[6];
    const float* g1  = (const float*)d_in[7];
    const float* b1  = (const float*)d_in[8];
    const float* g2  = (const float*)d_in[9];
    const float* b2  = (const float*)d_in[10];
    const float* W1  = (const float*)d_in[11];
    const float* W2  = (const float*)d_in[12];
    const float* gf  = (const float*)d_in[13];
    const float* bfp = (const float*)d_in[14];
    const float* Wf  = (const float*)d_in[15];
    float* out = (float*)d_out;

    char* ws = (char*)d_ws;
    size_t off = 0;
    auto alloc = [&](size_t bytes) {
        char* p = ws + off;
        off = (off + bytes + 255) & ~(size_t)255;
        return p;
    };
    ushort_t* WqT = (ushort_t*)alloc(4UL * 1048576 * 2);
    ushort_t* WkT = (ushort_t*)alloc(4UL * 1048576 * 2);
    ushort_t* WvT = (ushort_t*)alloc(4UL * 1048576 * 2);
    ushort_t* WoT = (ushort_t*)alloc(4UL * 1048576 * 2);
    ushort_t* W1T = (ushort_t*)alloc(4UL * 6291456 * 2);
    ushort_t* W2T = (ushort_t*)alloc(4UL * 6291456 * 2);
    ushort_t* WfT = (ushort_t*)alloc(32768000UL * 2);
    float*    h   = (float*)   alloc(2048UL * 1024 * 4);
    ushort_t* z   = (ushort_t*)alloc(2048UL * 1024 * 2);
    ushort_t* qb  = (ushort_t*)alloc(2048UL * 1024 * 2);
    ushort_t* kb  = (ushort_t*)alloc(2048UL * 1024 * 2);
    ushort_t* vT  = (ushort_t*)alloc(2048UL * 1024 * 2);
    ushort_t* ob  = (ushort_t*)alloc(2048UL * 1024 * 2);
    ushort_t* ub  = (ushort_t*)alloc(2048UL * 6144 * 2);
    (void)ws_size; (void)in_sizes; (void)n_in; (void)out_size;

    const dim3 tb(32, 8);
    transpose_conv<<<dim3(2,   32, 64), tb, 0, stream>>>(Wq, WqT, 64,    1024, 65536,   65536);
    transpose_conv<<<dim3(2,   32, 64), tb, 0, stream>>>(Wk, WkT, 64,    1024, 65536,   65536);
    transpose_conv<<<dim3(2,   32, 64), tb, 0, stream>>>(Wv, WvT, 64,    1024, 65536,   65536);
    transpose_conv<<<dim3(32,  32,  4), tb, 0, stream>>>(Wo, WoT, 1024,  1024, 1048576, 1048576);
    transpose_conv<<<dim3(192, 32,  4), tb, 0, stream>>>(W1, W1T, 6144,  1024, 6291456, 6291456);
    transpose_conv<<<dim3(32, 192,  4), tb, 0, stream>>>(W2, W2T, 1024,  6144, 6291456, 6291456);
    transpose_conv<<<dim3(1000,32,  1), tb, 0, stream>>>(Wf, WfT, 32000, 1024, 0,       0);

    embed_kernel<<<2048, 256, 0, stream>>>(x, emb, pos, h);

    for (int l = 0; l < 4; ++l) {
        const size_t wsq = (size_t)l * 1048576;
        const size_t wff = (size_t)l * 6291456;

        ln_kernel<<<2048, 256, 0, stream>>>(h, g1 + l * 1024, b1 + l * 1024, z);

        gemm128<EPI_BF16, 2><<<dim3(32, 8), 256, 0, stream>>>(
            z, WqT + wsq, qb, 1024, 1024, 1024, 1024, 0, 0, 0, 1.0f);
        gemm128<EPI_BF16, 2><<<dim3(32, 8), 256, 0, stream>>>(
            z, WkT + wsq, kb, 1024, 1024, 1024, 1024, 0, 0, 0, 1.0f);
        gemm128<EPI_TBF16, 2><<<dim3(16, 8, 2), 256, 0, stream>>>(
            z, WvT + wsq, vT, 1024, 1024, 1024, 1024, 1048576, 0, 1048576, 1.0f);

        flash_attn<<<dim3(16, 16, 2), 256, 0, stream>>>(qb, kb, vT, ob);

        gemm128<EPI_ADDF32, 2><<<dim3(32, 8), 256, 0, stream>>>(
            ob, WoT + wsq, h, 1024, 1024, 1024, 1024, 0, 0, 0, 1.0f);

        ln_kernel<<<2048, 256, 0, stream>>>(h, g2 + l * 1024, b2 + l * 1024, z);

        gemm128<EPI_GELU, 4><<<dim3(16, 48), 256, 0, stream>>>(
            z, W1T + wff, ub, 1024, 1024, 1024, 6144, 0, 0, 0, 1.0f);
        gemm128<EPI_ADDF32, 2><<<dim3(32, 8), 256, 0, stream>>>(
            ub, W2T + wff, h, 6144, 6144, 6144, 1024, 0, 0, 0, 1.0f);
    }

    ln_kernel<<<2048, 256, 0, stream>>>(h, gf, bfp, z);
    gemm128<EPI_F32, 4><<<dim3(16, 250), 256, 0, stream>>>(
        z, WfT, out, 1024, 1024, 1024, 32000, 0, 0, 0, 1.0f);
}

// Round 3
// 1229.728 us; speedup vs baseline: 2.0186x; 1.4704x over previous
//
#include <hip/hip_runtime.h>
#include <hip/hip_bf16.h>
#include <math.h>

// GPT forward, bf16 MFMA GEMMs + f32 residual stream.
// Dims: L=4, B=2, S=1024, E=1024, H=16, HD=64, FF=6144, V=32000, tokens T=2048.

typedef unsigned short ushort_t;
typedef unsigned short us8 __attribute__((ext_vector_type(8)));
typedef unsigned short us4 __attribute__((ext_vector_type(4)));
typedef __bf16 bf16x8 __attribute__((ext_vector_type(8)));
typedef float f32x4 __attribute__((ext_vector_type(4)));

#define LN_EPS 1e-5f

__device__ inline ushort_t f2bf(float f) {
    union { float f; unsigned u; } v; v.f = f;
    unsigned r = v.u + 0x7FFFu + ((v.u >> 16) & 1u);   // RNE
    return (ushort_t)(r >> 16);
}

#define GLD_LDS16(gp, lp)                                                  \
    __builtin_amdgcn_global_load_lds(                                      \
        (const __attribute__((address_space(1))) unsigned int*)(gp),       \
        (__attribute__((address_space(3))) unsigned int*)(lp), 16, 0, 0)

enum { EPI_F32 = 0, EPI_BF16 = 1, EPI_ADDF32 = 2, EPI_GELU = 3, EPI_TBF16 = 4,
       EPI_ATOM = 5, EPI_QKV = 6 };

// ---------------------------------------------------------------------------
// Pipelined GEMM (T2+T3+T4+T5+T1): C[M,N] = A[M,K] * Bt[N,K]^T, bf16 in.
// BM=128, BN=256, BK=64. 512 thr = 8 waves (2m x 4n), wave tile 64x64.
// Triple-buffered LDS (3 x 48 KB). Stage tile t+2 during tile t's 4 phases
// (target buf was fully read at end of tile t-1 -> race-free). Counted
// vmcnt(6) at tile boundary keeps one staged tile in flight. LDS XOR-swizzle
// elem ^= (row&7)<<3 on BOTH stage-source and ds_read.
// ---------------------------------------------------------------------------
template<int EPI>
__global__ __launch_bounds__(512)
void gemm8p(const ushort_t* __restrict__ A, const ushort_t* __restrict__ B,
            void* __restrict__ Cv, int mt, int K, int lda, int ldb, int ldc,
            long bsA, long bsB, long bsC)
{
    extern __shared__ ushort_t smem[];   // 3 bufs x (A 8192 + B 16384) ushorts

    // bijective XCD-chunk swizzle of the 1-D grid (m204 variant)
    const int nwg  = gridDim.x;
    const int orig = blockIdx.x;
    int wgid = orig;
    if (nwg >= 8) {
        const int q = nwg >> 3, r = nwg & 7;
        const int xcd = orig & 7, i = orig >> 3;
        wgid = (xcd < r ? xcd * (q + 1) : r * (q + 1) + (xcd - r) * q) + i;
    }
    const int m0 = (wgid % mt) * 128;
    const int n0 = (wgid / mt) * 256;

    A += (long)blockIdx.z * bsA;
    B += (long)blockIdx.z * bsB;

    const int tid  = threadIdx.x;
    const int lane = tid & 63;
    const int wid  = tid >> 6;
    const int wm   = wid >> 2, wn = wid & 3;
    const int cg   = lane >> 4, cl = lane & 15;
    const int lr   = lane >> 3;          // staging row within 8-row stripe
    const int lcc  = (lane & 7) * 8;     // staging col chunk (elements)

    const int nt = K >> 6;

    // stage one G::load unit: part 0-1 = A halves, 2-5 = B quarters
    auto stage = [&](int kt, int buf, int part) {
        ushort_t* base = smem + buf * 24576;
        const int k0 = kt * 64;
        if (part < 2) {
            const int rbase = part * 64 + wid * 8;
            const int row   = rbase + lr;
            const int col   = lcc ^ ((row & 7) << 3);
            GLD_LDS16(&A[(long)(m0 + row) * lda + k0 + col], base + rbase * 64);
        } else {
            const int rbase = (part - 2) * 64 + wid * 8;
            const int row   = rbase + lr;
            const int col   = lcc ^ ((row & 7) << 3);
            GLD_LDS16(&B[(long)(n0 + row) * ldb + k0 + col],
                      base + 8192 + rbase * 64);
        }
    };

    // prologue: stage tiles 0 and 1, wait for tile 0
    #pragma unroll
    for (int p = 0; p < 6; ++p) stage(0, 0, p);
    #pragma unroll
    for (int p = 0; p < 6; ++p) stage(1, 1, p);
    asm volatile("s_waitcnt vmcnt(6)" ::: "memory");
    __builtin_amdgcn_s_barrier();

    f32x4 acc[4][4] = {};

    for (int t = 0; t < nt; ++t) {
        const ushort_t* Aq = smem + (t % 3) * 24576;
        const ushort_t* Bq = Aq + 8192;
        const int sbuf = (t + 2) % 3;
        const bool do_stage = (t + 2 < nt);

        bf16x8 breg[4][2];
        #pragma unroll
        for (int p = 0; p < 4; ++p) {
            // ds_read A quadrant (2 x b128); B full (8 x b128) at phase 0
            const int rowA = wm * 64 + p * 16 + cl;
            bf16x8 aA[2];
            #pragma unroll
            for (int kk = 0; kk < 2; ++kk)
                aA[kk] = __builtin_bit_cast(bf16x8, *(const us8*)&Aq[
                    rowA * 64 + ((kk * 32 + cg * 8) ^ ((rowA & 7) << 3))]);
            if (p == 0) {
                #pragma unroll
                for (int nj = 0; nj < 4; ++nj) {
                    const int rowB = wn * 64 + nj * 16 + cl;
                    #pragma unroll
                    for (int kk = 0; kk < 2; ++kk)
                        breg[nj][kk] = __builtin_bit_cast(bf16x8, *(const us8*)&Bq[
                            rowB * 64 + ((kk * 32 + cg * 8) ^ ((rowB & 7) << 3))]);
                }
            }
            if (do_stage) {
                if (p == 0)      { stage(t + 2, sbuf, 0); stage(t + 2, sbuf, 1); }
                else if (p == 1) { stage(t + 2, sbuf, 2); stage(t + 2, sbuf, 3); }
                else if (p == 2) { stage(t + 2, sbuf, 4); }
                else             { stage(t + 2, sbuf, 5); }
            }
            __builtin_amdgcn_s_setprio(1);
            #pragma unroll
            for (int nj = 0; nj < 4; ++nj)
                #pragma unroll
                for (int kk = 0; kk < 2; ++kk)
                    acc[p][nj] = __builtin_amdgcn_mfma_f32_16x16x32_bf16(
                        aA[kk], breg[nj][kk], acc[p][nj], 0, 0, 0);
            __builtin_amdgcn_s_setprio(0);
            __builtin_amdgcn_s_barrier();
        }
        // tile boundary: next tile's stage must have landed
        if (do_stage) asm volatile("s_waitcnt vmcnt(6)" ::: "memory");
        else          asm volatile("s_waitcnt vmcnt(0)" ::: "memory");
        __builtin_amdgcn_s_barrier();
    }

    const int rb = m0 + wm * 64 + cg * 4;
    const int cb = n0 + wn * 64 + cl;

    #pragma unroll
    for (int mi = 0; mi < 4; ++mi) {
        #pragma unroll
        for (int nj = 0; nj < 4; ++nj) {
            const int colg = cb + nj * 16;
            if (EPI == EPI_QKV) {
                ushort_t* Q = (ushort_t*)Cv;
                if (n0 < 1024) {
                    #pragma unroll
                    for (int r = 0; r < 4; ++r)
                        Q[(long)(rb + mi * 16 + r) * 1024 + colg] = f2bf(acc[mi][nj][r]);
                } else if (n0 < 2048) {
                    #pragma unroll
                    for (int r = 0; r < 4; ++r)
                        Q[2097152 + (long)(rb + mi * 16 + r) * 1024 + (colg - 1024)] =
                            f2bf(acc[mi][nj][r]);
                } else {
                    ushort_t* Vt = Q + 4194304;
                    const int rowg = rb + mi * 16;
                    const long boff = (long)(rowg >> 10) * 1048576;
                    us4 o4;
                    #pragma unroll
                    for (int r = 0; r < 4; ++r) o4[r] = f2bf(acc[mi][nj][r]);
                    *(us4*)&Vt[boff + (long)(colg - 2048) * 1024 + (rowg & 1023)] = o4;
                }
            } else {
                #pragma unroll
                for (int r = 0; r < 4; ++r) {
                    const int  rowg = rb + mi * 16 + r;
                    const long off  = (long)rowg * ldc + colg;
                    const float val = acc[mi][nj][r];
                    if (EPI == EPI_F32) {
                        ((float*)Cv)[off] = val;
                    } else if (EPI == EPI_GELU) {
                        float g = 0.5f * val * (1.0f + erff(val * 0.70710678118654752f));
                        ((ushort_t*)Cv)[off] = f2bf(g);
                    } else if (EPI == EPI_ATOM) {
                        atomicAdd(&((float*)Cv)[off], val);
                    } else { // EPI_BF16
                        ((ushort_t*)Cv)[off] = f2bf(val);
                    }
                }
            }
        }
    }
}

// ---------------------------------------------------------------------------
// m97-style 64/128-wide GEMM kept for Wo (full-fill 256-block grid there).
// ---------------------------------------------------------------------------
template<int EPI, int MT>
__global__ __launch_bounds__(256)
void gemm128(const ushort_t* __restrict__ A, const ushort_t* __restrict__ B,
             void* __restrict__ Cv, int K, int lda, int ldb, int ldc,
             long bsA, long bsB, long bsC)
{
    const int m0 = blockIdx.x * (MT * 32);
    const int n0 = blockIdx.y * 128;
    A += (long)blockIdx.z * bsA;
    B += (long)blockIdx.z * bsB;

    __shared__ __align__(16) ushort_t As[MT * 32][64];
    __shared__ __align__(16) ushort_t Bs[128][64];

    const int tid  = threadIdx.x;
    const int lane = tid & 63;
    const int wid  = tid >> 6;
    const int wr   = wid >> 1, wc = wid & 1;
    const int lr   = lane >> 3;
    const int lc   = (lane & 7) * 8;
    const int cg   = lane >> 4;
    const int cl   = lane & 15;

    f32x4 acc[MT][4] = {};

    for (int k0 = 0; k0 < K; k0 += 64) {
        #pragma unroll
        for (int j = 0; j < MT; ++j) {
            const int r = wid * (8 * MT) + j * 8;
            GLD_LDS16(&A[(long)(m0 + r + lr) * lda + k0 + lc], &As[r][0]);
        }
        #pragma unroll
        for (int j = 0; j < 4; ++j) {
            const int r = wid * 32 + j * 8;
            GLD_LDS16(&B[(long)(n0 + r + lr) * ldb + k0 + lc], &Bs[r][0]);
        }
        __syncthreads();
        #pragma unroll
        for (int kk = 0; kk < 2; ++kk) {
            const int krd = kk * 32 + cg * 8;
            bf16x8 af[MT], bfr[4];
            #pragma unroll
            for (int mi = 0; mi < MT; ++mi)
                af[mi] = __builtin_bit_cast(bf16x8,
                    *(const us8*)&As[wr * (MT * 16) + mi * 16 + cl][krd]);
            #pragma unroll
            for (int nj = 0; nj < 4; ++nj)
                bfr[nj] = __builtin_bit_cast(bf16x8,
                    *(const us8*)&Bs[wc * 64 + nj * 16 + cl][krd]);
            #pragma unroll
            for (int mi = 0; mi < MT; ++mi)
                #pragma unroll
                for (int nj = 0; nj < 4; ++nj)
                    acc[mi][nj] = __builtin_amdgcn_mfma_f32_16x16x32_bf16(
                        af[mi], bfr[nj], acc[mi][nj], 0, 0, 0);
        }
        __syncthreads();
    }

    const int rb = m0 + wr * (MT * 16) + cg * 4;
    const int cb = n0 + wc * 64 + cl;

    #pragma unroll
    for (int mi = 0; mi < MT; ++mi)
        #pragma unroll
        for (int nj = 0; nj < 4; ++nj)
            #pragma unroll
            for (int r = 0; r < 4; ++r) {
                const long off = (long)(rb + mi * 16 + r) * ldc + cb + nj * 16;
                const float val = acc[mi][nj][r];
                if (EPI == EPI_ADDF32)      ((float*)Cv)[off] += val;
                else if (EPI == EPI_F32)    ((float*)Cv)[off] = val;
                else                        ((ushort_t*)Cv)[off] = f2bf(val);
            }
}

// ---------------------------------------------------------------------------
// Fused causal flash attention (unchanged math; block barrier removed —
// P_lds is wave-private; lgkmcnt orders write->read within the wave).
// ---------------------------------------------------------------------------
__global__ __launch_bounds__(256)
void flash_attn(const ushort_t* __restrict__ qb, const ushort_t* __restrict__ kb,
                const ushort_t* __restrict__ vT, ushort_t* __restrict__ ob)
{
    const int qt = gridDim.x - 1 - blockIdx.x;
    const int hh = blockIdx.y;
    const int bb = blockIdx.z;
    const int lane = threadIdx.x & 63;
    const int w    = threadIdx.x >> 6;
    const int cg   = lane >> 4;
    const int cl   = lane & 15;

    __shared__ __align__(16) ushort_t P_lds[4][16][72];

    const int q0 = qt * 64;
    const long tokQ = (long)bb * 1024 + q0 + w * 16 + cl;

    bf16x8 qf[2];
    #pragma unroll
    for (int kk = 0; kk < 2; ++kk)
        qf[kk] = __builtin_bit_cast(bf16x8,
            *(const us8*)&qb[tokQ * 1024 + hh * 64 + kk * 32 + cg * 8]);

    const ushort_t* kbase = kb + (long)bb * 1048576 + hh * 64;
    const ushort_t* vbase = vT + (long)bb * 1048576 + (long)hh * 65536;

    f32x4 o[4] = {};
    float m4[4], l4[4];
    #pragma unroll
    for (int r = 0; r < 4; ++r) { m4[r] = -1e30f; l4[r] = 0.0f; }

    for (int tt = 0; tt <= qt; ++tt) {
        const int t0 = tt * 64;
        f32x4 s[4] = {};
        __builtin_amdgcn_s_setprio(1);
        #pragma unroll
        for (int nj = 0; nj < 4; ++nj) {
            const ushort_t* kp = kbase + (long)(t0 + nj * 16 + cl) * 1024 + cg * 8;
            bf16x8 kf0 = __builtin_bit_cast(bf16x8, *(const us8*)kp);
            bf16x8 kf1 = __builtin_bit_cast(bf16x8, *(const us8*)(kp + 32));
            s[nj] = __builtin_amdgcn_mfma_f32_16x16x32_bf16(qf[0], kf0, s[nj], 0, 0, 0);
            s[nj] = __builtin_amdgcn_mfma_f32_16x16x32_bf16(qf[1], kf1, s[nj], 0, 0, 0);
        }
        __builtin_amdgcn_s_setprio(0);
        const bool diag = (tt == qt);
        float pm[4] = {-3e30f, -3e30f, -3e30f, -3e30f};
        #pragma unroll
        for (int nj = 0; nj < 4; ++nj)
            #pragma unroll
            for (int r = 0; r < 4; ++r) {
                float v = s[nj][r] * 0.125f;
                if (diag && (t0 + nj * 16 + cl) > (q0 + w * 16 + cg * 4 + r))
                    v = -1e30f;
                s[nj][r] = v;
                pm[r] = fmaxf(pm[r], v);
            }
        #pragma unroll
        for (int r = 0; r < 4; ++r)
            #pragma unroll
            for (int msk = 1; msk < 16; msk <<= 1)
                pm[r] = fmaxf(pm[r], __shfl_xor(pm[r], msk));
        float al[4], ps[4];
        #pragma unroll
        for (int r = 0; r < 4; ++r) {
            const float mn = fmaxf(m4[r], pm[r]);
            al[r] = __expf(m4[r] - mn);
            m4[r] = mn;
            ps[r] = 0.0f;
        }
        #pragma unroll
        for (int nj = 0; nj < 4; ++nj)
            #pragma unroll
            for (int r = 0; r < 4; ++r) {
                const float p = __expf(s[nj][r] - m4[r]);
                s[nj][r] = p;
                ps[r] += p;
            }
        #pragma unroll
        for (int r = 0; r < 4; ++r) {
            #pragma unroll
            for (int msk = 1; msk < 16; msk <<= 1)
                ps[r] += __shfl_xor(ps[r], msk);
            l4[r] = l4[r] * al[r] + ps[r];
        }
        #pragma unroll
        for (int nj = 0; nj < 4; ++nj)
            #pragma unroll
            for (int r = 0; r < 4; ++r) o[nj][r] *= al[r];
        #pragma unroll
        for (int nj = 0; nj < 4; ++nj)
            #pragma unroll
            for (int r = 0; r < 4; ++r)
                P_lds[w][cg * 4 + r][nj * 16 + cl] = f2bf(s[nj][r]);
        asm volatile("s_waitcnt lgkmcnt(0)" ::: "memory");
        __builtin_amdgcn_sched_barrier(0);
        bf16x8 pa[2];
        #pragma unroll
        for (int kk = 0; kk < 2; ++kk)
            pa[kk] = __builtin_bit_cast(bf16x8,
                *(const us8*)&P_lds[w][cl][kk * 32 + cg * 8]);
        __builtin_amdgcn_s_setprio(1);
        #pragma unroll
        for (int nj = 0; nj < 4; ++nj) {
            const ushort_t* vp = vbase + (long)(nj * 16 + cl) * 1024 + t0 + cg * 8;
            bf16x8 vf0 = __builtin_bit_cast(bf16x8, *(const us8*)vp);
            bf16x8 vf1 = __builtin_bit_cast(bf16x8, *(const us8*)(vp + 32));
            o[nj] = __builtin_amdgcn_mfma_f32_16x16x32_bf16(pa[0], vf0, o[nj], 0, 0, 0);
            o[nj] = __builtin_amdgcn_mfma_f32_16x16x32_bf16(pa[1], vf1, o[nj], 0, 0, 0);
        }
        __builtin_amdgcn_s_setprio(0);
    }

    #pragma unroll
    for (int r = 0; r < 4; ++r) {
        const float inv = 1.0f / l4[r];
        const long tok = (long)bb * 1024 + q0 + w * 16 + cg * 4 + r;
        #pragma unroll
        for (int nj = 0; nj < 4; ++nj)
            ob[tok * 1024 + hh * 64 + nj * 16 + cl] = f2bf(o[nj][r] * inv);
    }
}

// ---------------------------------------------------------------------------
// Tiled transpose + f32->bf16: out[(z%zmod)*bsout + (z/zmod)*bsout_hi + n*ldout+k]
// ---------------------------------------------------------------------------
__global__ __launch_bounds__(256)
void transpose_conv(const float* __restrict__ in, ushort_t* __restrict__ out,
                    long ldin, long ldout, long bsin, long bsout,
                    long bsout_hi, int zmod)
{
    __shared__ float tile[32][33];
    const int tx = threadIdx.x, ty = threadIdx.y;
    const long bin  = (long)blockIdx.z * bsin;
    const long bout = (long)(blockIdx.z % zmod) * bsout
                    + (long)(blockIdx.z / zmod) * bsout_hi;
    const int n0 = blockIdx.x * 32, k0 = blockIdx.y * 32;
    #pragma unroll
    for (int i = 0; i < 4; ++i)
        tile[ty + i * 8][tx] = in[bin + (long)(k0 + ty + i * 8) * ldin + n0 + tx];
    __syncthreads();
    #pragma unroll
    for (int i = 0; i < 4; ++i) {
        const int n = ty + i * 8;
        out[bout + (long)(n0 + n) * ldout + k0 + tx] = f2bf(tile[tx][n]);
    }
}

// ---------------------------------------------------------------------------
__global__ __launch_bounds__(256)
void embed_kernel(const int* __restrict__ x, const float* __restrict__ emb,
                  const float* __restrict__ pos, float* __restrict__ h)
{
    const int row = blockIdx.x, tid = threadIdx.x;
    const int s = row & 1023;
    const int idx = x[row];
    const float4 e = ((const float4*)(emb + (long)idx * 1024))[tid];
    const float4 p = ((const float4*)(pos + (long)s * 1024))[tid];
    float4 o; o.x = e.x + p.x; o.y = e.y + p.y; o.z = e.z + p.z; o.w = e.w + p.w;
    ((float4*)(h + (long)row * 1024))[tid] = o;
}

// ---------------------------------------------------------------------------
__global__ __launch_bounds__(256)
void ln_kernel(const float* __restrict__ x, const float* __restrict__ g,
               const float* __restrict__ b, ushort_t* __restrict__ z)
{
    const int row = blockIdx.x, tid = threadIdx.x;
    const float4 v = ((const float4*)(x + (long)row * 1024))[tid];
    float s  = v.x + v.y + v.z + v.w;
    float sq = v.x * v.x + v.y * v.y + v.z * v.z + v.w * v.w;
    #pragma unroll
    for (int o = 32; o > 0; o >>= 1) { s += __shfl_down(s, o); sq += __shfl_down(sq, o); }
    __shared__ float ls[4], lq[4];
    if ((tid & 63) == 0) { ls[tid >> 6] = s; lq[tid >> 6] = sq; }
    __syncthreads();
    s  = ls[0] + ls[1] + ls[2] + ls[3];
    sq = lq[0] + lq[1] + lq[2] + lq[3];
    const float mu   = s * (1.0f / 1024.0f);
    const float var  = sq * (1.0f / 1024.0f) - mu * mu;
    const float rstd = rsqrtf(var + LN_EPS);
    const float4 gg = ((const float4*)g)[tid];
    const float4 bb = ((const float4*)b)[tid];
    us4 o4;
    o4[0] = f2bf((v.x - mu) * rstd * gg.x + bb.x);
    o4[1] = f2bf((v.y - mu) * rstd * gg.y + bb.y);
    o4[2] = f2bf((v.z - mu) * rstd * gg.z + bb.z);
    o4[3] = f2bf((v.w - mu) * rstd * gg.w + bb.w);
    *(us4*)(z + (long)row * 1024 + tid * 4) = o4;
}

// ---------------------------------------------------------------------------
extern "C" void kernel_launch(void* const* d_in, const int* in_sizes, int n_in,
                              void* d_out, int out_size, void* d_ws, size_t ws_size,
                              hipStream_t stream)
{
    const int*   x   = (const int*)  d_in[0];
    const float* emb = (const float*)d_in[1];
    const float* pos = (const float*)d_in[2];
    const float* Wq  = (const float*)d_in[3];
    const float* Wk  = (const float*)d_in[4];
    const float* Wv  = (const float*)d_in[5];
    const float* Wo  = (const float*)d_in[6];
    const float* g1  = (const float*)d_in[7];
    const float* b1  = (const float*)d_in[8];
    const float* g2  = (const float*)d_in[9];
    const float* b2  = (const float*)d_in[10];
    const float* W1  = (const float*)d_in[11];
    const float* W2  = (const float*)d_in[12];
    const float* gf  = (const float*)d_in[13];
    const float* bfp = (const float*)d_in[14];
    const float* Wf  = (const float*)d_in[15];
    float* out = (float*)d_out;

    char* ws = (char*)d_ws;
    size_t off = 0;
    auto alloc = [&](size_t bytes) {
        char* p = ws + off;
        off = (off + bytes + 255) & ~(size_t)255;
        return p;
    };
    ushort_t* WqkvT = (ushort_t*)alloc(4UL * 3145728 * 2);   // [L][3][1024][1024]
    ushort_t* WoT   = (ushort_t*)alloc(4UL * 1048576 * 2);
    ushort_t* W1T   = (ushort_t*)alloc(4UL * 6291456 * 2);
    ushort_t* W2T   = (ushort_t*)alloc(4UL * 6291456 * 2);
    ushort_t* WfT   = (ushort_t*)alloc(32768000UL * 2);
    float*    h     = (float*)   alloc(2048UL * 1024 * 4);
    ushort_t* z     = (ushort_t*)alloc(2048UL * 1024 * 2);
    ushort_t* qb    = (ushort_t*)alloc(3UL * 2048 * 1024 * 2); // q | k | vT
    ushort_t* kb    = qb + 2097152;
    ushort_t* vT    = qb + 4194304;
    ushort_t* ob    = (ushort_t*)alloc(2048UL * 1024 * 2);
    ushort_t* ub    = (ushort_t*)alloc(2048UL * 6144 * 2);
    (void)ws_size; (void)in_sizes; (void)n_in; (void)out_size;

    const int LDSB = 3 * 49152;   // 144 KiB dynamic LDS for gemm8p
    hipFuncSetAttribute((const void*)&gemm8p<EPI_F32>,
                        hipFuncAttributeMaxDynamicSharedMemorySize, LDSB);
    hipFuncSetAttribute((const void*)&gemm8p<EPI_GELU>,
                        hipFuncAttributeMaxDynamicSharedMemorySize, LDSB);
    hipFuncSetAttribute((const void*)&gemm8p<EPI_ATOM>,
                        hipFuncAttributeMaxDynamicSharedMemorySize, LDSB);
    hipFuncSetAttribute((const void*)&gemm8p<EPI_QKV>,
                        hipFuncAttributeMaxDynamicSharedMemorySize, LDSB);

    const dim3 tb(32, 8);
    // q/k/v -> fused [L][3][1024 out][1024 K] (B^T layout)
    transpose_conv<<<dim3(2,   32, 64), tb, 0, stream>>>(Wq, WqkvT,           64, 1024, 65536, 65536, 3145728, 16);
    transpose_conv<<<dim3(2,   32, 64), tb, 0, stream>>>(Wk, WqkvT + 1048576, 64, 1024, 65536, 65536, 3145728, 16);
    transpose_conv<<<dim3(2,   32, 64), tb, 0, stream>>>(Wv, WqkvT + 2097152, 64, 1024, 65536, 65536, 3145728, 16);
    transpose_conv<<<dim3(32,  32,  4), tb, 0, stream>>>(Wo, WoT, 1024,  1024, 1048576, 1048576, 0, 4);
    transpose_conv<<<dim3(192, 32,  4), tb, 0, stream>>>(W1, W1T, 6144,  1024, 6291456, 6291456, 0, 4);
    transpose_conv<<<dim3(32, 192,  4), tb, 0, stream>>>(W2, W2T, 1024,  6144, 6291456, 6291456, 0, 4);
    transpose_conv<<<dim3(1000,32,  1), tb, 0, stream>>>(Wf, WfT, 32000, 1024, 0,       0,       0, 1);

    embed_kernel<<<2048, 256, 0, stream>>>(x, emb, pos, h);

    for (int l = 0; l < 4; ++l) {
        const size_t wsq = (size_t)l * 1048576;
        const size_t wff = (size_t)l * 6291456;

        ln_kernel<<<2048, 256, 0, stream>>>(h, g1 + l * 1024, b1 + l * 1024, z);

        // fused QKV: [2048,3072] = z @ WqkvT^T   (192 blocks)
        gemm8p<EPI_QKV><<<dim3(16 * 12, 1, 1), 512, LDSB, stream>>>(
            z, WqkvT + (size_t)l * 3145728, qb, 16, 1024, 1024, 1024, 0, 0, 0, 0);

        flash_attn<<<dim3(16, 16, 2), 256, 0, stream>>>(qb, kb, vT, ob);

        // h += o @ Wo  (m97 kernel, full-fill 256-block grid)
        gemm128<EPI_ADDF32, 2><<<dim3(32, 8), 256, 0, stream>>>(
            ob, WoT + wsq, h, 1024, 1024, 1024, 1024, 0, 0, 0);

        ln_kernel<<<2048, 256, 0, stream>>>(h, g2 + l * 1024, b2 + l * 1024, z);

        // u = gelu(z @ W1)   (384 blocks)
        gemm8p<EPI_GELU><<<dim3(16 * 24, 1, 1), 512, LDSB, stream>>>(
            z, W1T + wff, ub, 16, 1024, 1024, 1024, 6144, 0, 0, 0);
        // h += u @ W2, K split 4 ways with atomic f32 accumulate (256 blocks)
        gemm8p<EPI_ATOM><<<dim3(16 * 4, 1, 4), 512, LDSB, stream>>>(
            ub, W2T + wff, h, 16, 1536, 6144, 6144, 1024, 1536, 1536, 0);
    }

    ln_kernel<<<2048, 256, 0, stream>>>(h, gf, bfp, z);
    // logits = z @ Wf -> f32 [2048, 32000]   (2000 blocks)
    gemm8p<EPI_F32><<<dim3(16 * 125, 1, 1), 512, LDSB, stream>>>(
        z, WfT, out, 16, 1024, 1024, 1024, 32000, 0, 0, 0);
}